// Round 10
// baseline (68.785 us; speedup 1.0000x reference)
//
#include <hip/hip_runtime.h>
#include <math.h>

#define NTX_EPS 1e-8f

typedef __fp16 half8  __attribute__((ext_vector_type(8)));
typedef __fp16 half4v __attribute__((ext_vector_type(4)));
typedef __fp16 half2v __attribute__((ext_vector_type(2)));
typedef float  f32x4  __attribute__((ext_vector_type(4)));

union H4 { half4v v4; half2v v2[2]; };

// Kernel 1: 1792 blocks x 256 threads (4 waves). Block = (b, slot):
// slot 0..3 -> lvl0 d-range slot*1024; 4..5 -> lvl1; 6 -> lvl2.
//
// R1-R9 lesson: every prior kernel read 16 rows in parallel with 32-128B
// granules at 4-16KB pow-2 stride -> requests concentrate on few channel/
// L3-slice interleave bins; all variants stuck at ~90us/dispatch, warm==cold,
// all pipes idle. THIS round: global reads are CONTIGUOUS 4KB spans (one
// row-chunk per instruction, 256 threads x float4 sequential), staged to LDS
// as f16, then the verified register-MFMA Gram reads fragments from LDS.
// Lane l feeds Gram row l&15, k-group l>>4; one half8 is both A and B operand;
// mfma(t,t)->tt, mfma(t,r)->tr, mfma(r,r)->rr norms. C/D: col=l&15, row=kg*4+r.
__global__ __launch_bounds__(256, 1)   // allow high VGPR: keep load burst hoisted
void ntxent_partial(const float* __restrict__ ts0, const float* __restrict__ rs0,
                    const float* __restrict__ ts1, const float* __restrict__ rs1,
                    const float* __restrict__ ts2, const float* __restrict__ rs2,
                    float* __restrict__ ws, float* __restrict__ out)
{
    __shared__ __fp16 Mt[32][1032];   // 66KB: rows 0-15 ts, 16-31 rs; +8 pad
    __shared__ float redTT[4][256];
    __shared__ float redTR[4][256];
    __shared__ float redRR[4][16];
    __shared__ float Gs[16][33];
    __shared__ float rn2[16], tnS[16], rnS[16];

    const int bid  = blockIdx.x;
    const int b    = bid / 7;
    const int slot = bid % 7;

    const float* tp; const float* rp; int D; int chunk0;
    if (slot < 4)      { tp = ts0; rp = rs0; D = 4096; chunk0 = slot; }
    else if (slot < 6) { tp = ts1; rp = rs1; D = 2048; chunk0 = slot - 4; }
    else               { tp = ts2; rp = rs2; D = 1024; chunk0 = 0; }

    const int t = threadIdx.x;

    // ---- staging: 32 instructions, each a fully-contiguous 4KB row-chunk ----
    float4 burst[32];
#pragma unroll
    for (int i = 0; i < 32; ++i) {
        const float* src = (i < 16)
            ? tp + ((size_t)b * 16 + i)        * (size_t)D + (size_t)chunk0 * 1024
            : rp + ((size_t)b * 16 + (i - 16)) * (size_t)D + (size_t)chunk0 * 1024;
        burst[i] = *(const float4*)(src + t * 4);
    }
#pragma unroll
    for (int i = 0; i < 32; ++i) {
        H4 u;
        u.v2[0] = __builtin_amdgcn_cvt_pkrtz(burst[i].x, burst[i].y);
        u.v2[1] = __builtin_amdgcn_cvt_pkrtz(burst[i].z, burst[i].w);
        *(half4v*)&Mt[i][t * 4] = u.v4;
    }
    __syncthreads();

    // ---- compute: wave w owns K-quarter w*256 (8 K-steps of 32) ----
    const int w   = t >> 6;
    const int l   = t & 63;
    const int row = l & 15;
    const int kg  = l >> 4;

    f32x4 acc_tt = {0.f, 0.f, 0.f, 0.f};
    f32x4 acc_tr = {0.f, 0.f, 0.f, 0.f};
    f32x4 acc_rr = {0.f, 0.f, 0.f, 0.f};

    const int kb = w * 256 + kg * 8;
#pragma unroll
    for (int s = 0; s < 8; ++s) {
        half8 tf = *(const half8*)&Mt[row][kb + s * 32];
        half8 rf = *(const half8*)&Mt[16 + row][kb + s * 32];
        acc_tt = __builtin_amdgcn_mfma_f32_16x16x32_f16(tf, tf, acc_tt, 0, 0, 0);
        acc_tr = __builtin_amdgcn_mfma_f32_16x16x32_f16(tf, rf, acc_tr, 0, 0, 0);
        acc_rr = __builtin_amdgcn_mfma_f32_16x16x32_f16(rf, rf, acc_rr, 0, 0, 0);
    }

    // C/D layout (m89): col = l&15, row index = kg*4 + r.
    const int m = row;
#pragma unroll
    for (int r = 0; r < 4; ++r) {
        const int n = kg * 4 + r;
        redTT[w][n * 16 + m] = acc_tt[r];
        redTR[w][n * 16 + m] = acc_tr[r];
    }
    if ((m >> 2) == kg) redRR[w][m] = acc_rr[m & 3];
    __syncthreads();

    // combine the 4 wave partials; one thread per Gram element
    const int n  = t >> 4;
    const int mm = t & 15;
    const float tt = redTT[0][t] + redTT[1][t] + redTT[2][t] + redTT[3][t];
    const float tr = redTR[0][t] + redTR[1][t] + redTR[2][t] + redTR[3][t];

    if (slot != 6) {
        float* slotp = ws + (size_t)(b * 6 + slot) * 528;
        slotp[n * 32 + mm]      = tt;
        slotp[n * 32 + 16 + mm] = tr;
        if (t < 16)
            slotp[512 + t] = redRR[0][t] + redRR[1][t] + redRR[2][t] + redRR[3][t];
        return;
    }

    // ---- slot 6 (level 2): finish the loss in-kernel ----
    Gs[n][mm]      = tt;
    Gs[n][16 + mm] = tr;
    if (t < 16)
        rn2[t] = redRR[0][t] + redRR[1][t] + redRR[2][t] + redRR[3][t];
    __syncthreads();

    if (t < 16) {
        tnS[t] = fmaxf(sqrtf(Gs[t][t]), NTX_EPS);
        rnS[t] = fmaxf(sqrtf(rn2[t]), NTX_EPS);
    }
    __syncthreads();

    float loss = 0.f;
    if (t < 16) {
        const int nn = t;
        const float itn = 2.0f / tnS[nn];        // includes 1/temperature
        float lg[32];
#pragma unroll
        for (int j = 0; j < 16; ++j)
            lg[j] = Gs[nn][16 + j] * itn / rnS[j];     // s_tr row
#pragma unroll
        for (int k = 0; k < 16; ++k)
            lg[16 + k] = Gs[nn][k] * itn / tnS[k];     // s_tt row
        const float pos = lg[nn];
        float mx = -3.4e38f;
#pragma unroll
        for (int j = 0; j < 32; ++j)
            mx = (j == 16 + nn) ? mx : fmaxf(mx, lg[j]);   // exclude tt diag
        float sm = 0.f;
#pragma unroll
        for (int j = 0; j < 32; ++j)
            sm += (j == 16 + nn) ? 0.f : expf(lg[j] - mx);
        loss = logf(sm) + mx - pos;
    }
    loss += __shfl_xor(loss, 1, 64);
    loss += __shfl_xor(loss, 2, 64);
    loss += __shfl_xor(loss, 4, 64);
    loss += __shfl_xor(loss, 8, 64);
    if (t == 0) atomicAdd(out, loss * (1.0f / 512.0f));
}

// Kernel 2: sum partial Grams for levels 0/1 and do the logsumexp.
// grid = B*2 (b = bid>>1, lvl = bid&1), block = 64.
__global__ __launch_bounds__(64)
void ntxent_finish(const float* __restrict__ ws, float* __restrict__ out)
{
    __shared__ float G[16][33];
    __shared__ float rn2s[16];
    __shared__ float tn[16], rn[16];

    const int bid = blockIdx.x;
    const int b   = bid >> 1;
    const int lvl = bid & 1;
    const int base = b * 6 + (lvl ? 4 : 0);
    const int cnt  = lvl ? 2 : 4;
    const int l = threadIdx.x;

    for (int e = l; e < 512; e += 64) {
        float s = 0.f;
        for (int c = 0; c < cnt; ++c) s += ws[(size_t)(base + c) * 528 + e];
        G[e >> 5][e & 31] = s;
    }
    if (l < 16) {
        float s = 0.f;
        for (int c = 0; c < cnt; ++c) s += ws[(size_t)(base + c) * 528 + 512 + l];
        rn2s[l] = s;
    }
    __syncthreads();
    if (l < 16) {
        tn[l] = fmaxf(sqrtf(G[l][l]), NTX_EPS);
        rn[l] = fmaxf(sqrtf(rn2s[l]), NTX_EPS);
    }
    __syncthreads();

    float loss = 0.f;
    if (l < 16) {
        const int n = l;
        const float itn = 2.0f / tn[n];
        float lg[32];
#pragma unroll
        for (int j = 0; j < 16; ++j)
            lg[j] = G[n][16 + j] * itn / rn[j];
#pragma unroll
        for (int k = 0; k < 16; ++k)
            lg[16 + k] = G[n][k] * itn / tn[k];
        const float pos = lg[n];
        float mx = -3.4e38f;
#pragma unroll
        for (int j = 0; j < 32; ++j)
            mx = (j == 16 + n) ? mx : fmaxf(mx, lg[j]);
        float sm = 0.f;
#pragma unroll
        for (int j = 0; j < 32; ++j)
            sm += (j == 16 + n) ? 0.f : expf(lg[j] - mx);
        loss = logf(sm) + mx - pos;
    }
    loss += __shfl_xor(loss, 1, 64);
    loss += __shfl_xor(loss, 2, 64);
    loss += __shfl_xor(loss, 4, 64);
    loss += __shfl_xor(loss, 8, 64);
    if (l == 0) atomicAdd(out, loss * (1.0f / 512.0f));
}

extern "C" void kernel_launch(void* const* d_in, const int* in_sizes, int n_in,
                              void* d_out, int out_size, void* d_ws, size_t ws_size,
                              hipStream_t stream) {
    const float* ts0 = (const float*)d_in[0];
    const float* rs0 = (const float*)d_in[1];
    const float* ts1 = (const float*)d_in[2];
    const float* rs1 = (const float*)d_in[3];
    const float* ts2 = (const float*)d_in[4];
    const float* rs2 = (const float*)d_in[5];
    float* out = (float*)d_out;
    float* ws  = (float*)d_ws;

    hipMemsetAsync(out, 0, sizeof(float), stream);

    const int B = in_sizes[0] / (16 * 4096);   // 256
    hipLaunchKernelGGL(ntxent_partial, dim3(B * 7), dim3(256), 0, stream,
                       ts0, rs0, ts1, rs1, ts2, rs2, ws, out);
    hipLaunchKernelGGL(ntxent_finish, dim3(B * 2), dim3(64), 0, stream,
                       ws, out);
}

// Round 11
// 62.466 us; speedup vs baseline: 1.1012x; 1.1012x over previous
//
#include <hip/hip_runtime.h>
#include <math.h>

#define NTX_EPS 1e-8f

typedef __fp16 half8 __attribute__((ext_vector_type(8)));
typedef __fp16 half2v __attribute__((ext_vector_type(2)));
typedef float f32x4 __attribute__((ext_vector_type(4)));

union H8 { half8 v8; half2v v2[4]; };

__device__ __forceinline__ half8 pack8(const float4& a, const float4& b) {
    H8 u;
    u.v2[0] = __builtin_amdgcn_cvt_pkrtz(a.x, a.y);
    u.v2[1] = __builtin_amdgcn_cvt_pkrtz(a.z, a.w);
    u.v2[2] = __builtin_amdgcn_cvt_pkrtz(b.x, b.y);
    u.v2[3] = __builtin_amdgcn_cvt_pkrtz(b.z, b.w);
    return u.v8;
}

// ws layout (floats):
//   [ (b*6+slot)*528 ]        : 528-float Gram partials, slots 0..5
//   [ LOSS_OFF + b*3 + lvl ]  : per-(batch,level) loss; lvl2 written by K1,
//                               lvl0/1 by K2; all 768 summed by K3.
#define LOSS_OFF (256 * 6 * 528)

// Kernel 1: 1792 blocks x 64 threads (ONE wave per block) — exact R7
// structure (best wall so far), minus the atomicAdd: slot-6 loss goes to a
// private ws cell. R1-R10 showed structure/occupancy/coalescing all neutral;
// the last invariant is same-address device atomics (256 here + 512 in
// finish) — this round removes all of them (single-variable A/B vs R7).
__global__ __launch_bounds__(64)
void ntxent_partial(const float* __restrict__ ts0, const float* __restrict__ rs0,
                    const float* __restrict__ ts1, const float* __restrict__ rs1,
                    const float* __restrict__ ts2, const float* __restrict__ rs2,
                    float* __restrict__ ws)
{
    __shared__ float Gs[16][33];
    __shared__ float rn2[16];
    __shared__ float tnS[16], rnS[16];

    const int bid  = blockIdx.x;
    const int b    = bid / 7;
    const int slot = bid % 7;

    const float* tp; const float* rp; int D; int chunk0;
    if (slot < 4)      { tp = ts0; rp = rs0; D = 4096; chunk0 = slot; }
    else if (slot < 6) { tp = ts1; rp = rs1; D = 2048; chunk0 = slot - 4; }
    else               { tp = ts2; rp = rs2; D = 1024; chunk0 = 0; }

    const int l   = threadIdx.x;
    const int row = l & 15;       // A-row / B-col index this lane feeds
    const int kg  = l >> 4;       // 0..3 k-group

    const size_t rbase = (size_t)b * 16 * D + (size_t)row * D
                       + (size_t)chunk0 * 1024 + (size_t)kg * 8;
    const float* tsrc = tp + rbase;
    const float* rsrc = rp + rbase;

    f32x4 acc_tt = {0.f, 0.f, 0.f, 0.f};
    f32x4 acc_tr = {0.f, 0.f, 0.f, 0.f};
    f32x4 acc_rr = {0.f, 0.f, 0.f, 0.f};

    // depth-1 register staging, manual ping-pong (static names only)
    float4 ta = *(const float4*)(tsrc);
    float4 tb = *(const float4*)(tsrc + 4);
    float4 ra = *(const float4*)(rsrc);
    float4 rb = *(const float4*)(rsrc + 4);

#pragma unroll 2
    for (int s = 0; s < 32; ++s) {        // 32 K-steps of 32 (1024 floats)
        float4 nta, ntb, nra, nrb;
        if (s + 1 < 32) {
            const float* tn = tsrc + (size_t)(s + 1) * 32;
            const float* rn = rsrc + (size_t)(s + 1) * 32;
            nta = *(const float4*)(tn);
            ntb = *(const float4*)(tn + 4);
            nra = *(const float4*)(rn);
            nrb = *(const float4*)(rn + 4);
        }
        half8 tf = pack8(ta, tb);
        half8 rf = pack8(ra, rb);
        acc_tt = __builtin_amdgcn_mfma_f32_16x16x32_f16(tf, tf, acc_tt, 0, 0, 0);
        acc_tr = __builtin_amdgcn_mfma_f32_16x16x32_f16(tf, rf, acc_tr, 0, 0, 0);
        acc_rr = __builtin_amdgcn_mfma_f32_16x16x32_f16(rf, rf, acc_rr, 0, 0, 0);
        ta = nta; tb = ntb; ra = nra; rb = nrb;
    }

    // C/D layout (m89-verified, dtype-independent): col = l&15, row = kg*4+r.
    const int m = row;                    // output column this lane holds
    if (slot != 6) {
        float* slotp = ws + (size_t)(b * 6 + slot) * 528;
#pragma unroll
        for (int r = 0; r < 4; ++r) {
            const int n = kg * 4 + r;
            slotp[n * 32 + m]      = acc_tt[r];
            slotp[n * 32 + 16 + m] = acc_tr[r];
        }
        if ((m >> 2) == kg) slotp[512 + m] = acc_rr[m & 3];  // rr diagonal
        return;
    }

    // ---- slot 6 (level 2): finish the loss in-kernel ----
#pragma unroll
    for (int r = 0; r < 4; ++r) {
        const int n = kg * 4 + r;
        Gs[n][m]      = acc_tt[r];
        Gs[n][16 + m] = acc_tr[r];
    }
    if ((m >> 2) == kg) rn2[m] = acc_rr[m & 3];
    __syncthreads();

    if (l < 16) {
        tnS[l] = fmaxf(sqrtf(Gs[l][l]), NTX_EPS);
        rnS[l] = fmaxf(sqrtf(rn2[l]), NTX_EPS);
    }
    __syncthreads();

    float loss = 0.f;
    if (l < 16) {
        const int n = l;
        const float itn = 2.0f / tnS[n];        // includes 1/temperature
        float lg[32];
#pragma unroll
        for (int j = 0; j < 16; ++j)
            lg[j] = Gs[n][16 + j] * itn / rnS[j];     // s_tr row
#pragma unroll
        for (int k = 0; k < 16; ++k)
            lg[16 + k] = Gs[n][k] * itn / tnS[k];     // s_tt row
        const float pos = lg[n];
        float mx = -3.4e38f;
#pragma unroll
        for (int j = 0; j < 32; ++j)
            mx = (j == 16 + n) ? mx : fmaxf(mx, lg[j]);   // exclude tt diag
        float sm = 0.f;
#pragma unroll
        for (int j = 0; j < 32; ++j)
            sm += (j == 16 + n) ? 0.f : expf(lg[j] - mx);
        loss = logf(sm) + mx - pos;
    }
    loss += __shfl_xor(loss, 1, 64);
    loss += __shfl_xor(loss, 2, 64);
    loss += __shfl_xor(loss, 4, 64);
    loss += __shfl_xor(loss, 8, 64);
    if (l == 0) ws[LOSS_OFF + b * 3 + 2] = loss;    // NO atomic
}

// Kernel 2: sum partial Grams for levels 0/1 and do the logsumexp.
// grid = B*2 (b = bid>>1, lvl = bid&1), block = 64. Loss -> ws cell (no atomic).
__global__ __launch_bounds__(64)
void ntxent_finish(const float* __restrict__ ws_in, float* __restrict__ ws)
{
    __shared__ float G[16][33];
    __shared__ float rn2s[16];
    __shared__ float tn[16], rn[16];

    const int bid = blockIdx.x;
    const int b   = bid >> 1;
    const int lvl = bid & 1;
    const int base = b * 6 + (lvl ? 4 : 0);
    const int cnt  = lvl ? 2 : 4;
    const int l = threadIdx.x;

    for (int e = l; e < 512; e += 64) {
        float s = 0.f;
        for (int c = 0; c < cnt; ++c) s += ws_in[(size_t)(base + c) * 528 + e];
        G[e >> 5][e & 31] = s;
    }
    if (l < 16) {
        float s = 0.f;
        for (int c = 0; c < cnt; ++c) s += ws_in[(size_t)(base + c) * 528 + 512 + l];
        rn2s[l] = s;
    }
    __syncthreads();
    if (l < 16) {
        tn[l] = fmaxf(sqrtf(G[l][l]), NTX_EPS);
        rn[l] = fmaxf(sqrtf(rn2s[l]), NTX_EPS);
    }
    __syncthreads();

    float loss = 0.f;
    if (l < 16) {
        const int n = l;
        const float itn = 2.0f / tn[n];
        float lg[32];
#pragma unroll
        for (int j = 0; j < 16; ++j)
            lg[j] = G[n][16 + j] * itn / rn[j];
#pragma unroll
        for (int k = 0; k < 16; ++k)
            lg[16 + k] = G[n][k] * itn / tn[k];
        const float pos = lg[n];
        float mx = -3.4e38f;
#pragma unroll
        for (int j = 0; j < 32; ++j)
            mx = (j == 16 + n) ? mx : fmaxf(mx, lg[j]);
        float sm = 0.f;
#pragma unroll
        for (int j = 0; j < 32; ++j)
            sm += (j == 16 + n) ? 0.f : expf(lg[j] - mx);
        loss = logf(sm) + mx - pos;
    }
    loss += __shfl_xor(loss, 1, 64);
    loss += __shfl_xor(loss, 2, 64);
    loss += __shfl_xor(loss, 4, 64);
    loss += __shfl_xor(loss, 8, 64);
    if (l == 0) ws[LOSS_OFF + b * 3 + lvl] = loss;  // NO atomic
}

// Kernel 3: single block sums the 768 per-(b,lvl) losses -> out[0].
// Replaces both the hipMemsetAsync and all atomics.
__global__ __launch_bounds__(256)
void ntxent_sum(const float* __restrict__ ws, float* __restrict__ out)
{
    __shared__ float partial[4];
    const int t = threadIdx.x;
    float s = 0.f;
    for (int i = t; i < 768; i += 256) s += ws[LOSS_OFF + i];
    s += __shfl_xor(s, 1, 64);
    s += __shfl_xor(s, 2, 64);
    s += __shfl_xor(s, 4, 64);
    s += __shfl_xor(s, 8, 64);
    s += __shfl_xor(s, 16, 64);
    s += __shfl_xor(s, 32, 64);
    if ((t & 63) == 0) partial[t >> 6] = s;
    __syncthreads();
    if (t == 0)
        out[0] = (partial[0] + partial[1] + partial[2] + partial[3])
                 * (1.0f / 512.0f);
}

extern "C" void kernel_launch(void* const* d_in, const int* in_sizes, int n_in,
                              void* d_out, int out_size, void* d_ws, size_t ws_size,
                              hipStream_t stream) {
    const float* ts0 = (const float*)d_in[0];
    const float* rs0 = (const float*)d_in[1];
    const float* ts1 = (const float*)d_in[2];
    const float* rs1 = (const float*)d_in[3];
    const float* ts2 = (const float*)d_in[4];
    const float* rs2 = (const float*)d_in[5];
    float* out = (float*)d_out;
    float* ws  = (float*)d_ws;

    const int B = in_sizes[0] / (16 * 4096);   // 256
    hipLaunchKernelGGL(ntxent_partial, dim3(B * 7), dim3(64), 0, stream,
                       ts0, rs0, ts1, rs1, ts2, rs2, ws);
    hipLaunchKernelGGL(ntxent_finish, dim3(B * 2), dim3(64), 0, stream,
                       ws, ws);
    hipLaunchKernelGGL(ntxent_sum, dim3(1), dim3(256), 0, stream,
                       ws, out);
}

// Round 12
// 60.331 us; speedup vs baseline: 1.1401x; 1.0354x over previous
//
#include <hip/hip_runtime.h>
#include <math.h>

#define NTX_EPS 1e-8f

typedef __fp16 half8 __attribute__((ext_vector_type(8)));
typedef __fp16 half2v __attribute__((ext_vector_type(2)));
typedef float f32x4 __attribute__((ext_vector_type(4)));

union H8 { half8 v8; half2v v2[4]; };

__device__ __forceinline__ half8 pack8(const float4& a, const float4& b) {
    H8 u;
    u.v2[0] = __builtin_amdgcn_cvt_pkrtz(a.x, a.y);
    u.v2[1] = __builtin_amdgcn_cvt_pkrtz(a.z, a.w);
    u.v2[2] = __builtin_amdgcn_cvt_pkrtz(b.x, b.y);
    u.v2[3] = __builtin_amdgcn_cvt_pkrtz(b.z, b.w);
    return u.v8;
}

// Opaque async load: compiler cannot serialize/recycle these into a dependent
// chain (R8-R10: allocator collapsed every HIP-level burst to 32-40 VGPR and
// ~2-4 loads in flight). Each call issues exactly one global_load_dwordx4.
__device__ __forceinline__ float4 gl4(const float* p) {
    float4 d;
    asm volatile("global_load_dwordx4 %0, %1, off" : "=v"(d) : "v"(p) : "memory");
    return d;
}
// Counted wait + scheduling fence (guide rule #18: register-only consumers can
// be hoisted past a waitcnt asm unless followed by sched_barrier(0)).
#define WAITVM(n) do { asm volatile("s_waitcnt vmcnt(" #n ")" ::: "memory"); \
                       __builtin_amdgcn_sched_barrier(0); } while (0)

#define ISSUE(g, s) \
    float4 g##T0 = gl4(tsrc + (s) * 32); \
    float4 g##T1 = gl4(tsrc + (s) * 32 + 4); \
    float4 g##R0 = gl4(rsrc + (s) * 32); \
    float4 g##R1 = gl4(rsrc + (s) * 32 + 4);

#define COMPUTE(g) { \
    half8 tf = pack8(g##T0, g##T1); \
    half8 rf = pack8(g##R0, g##R1); \
    acc_tt = __builtin_amdgcn_mfma_f32_16x16x32_f16(tf, tf, acc_tt, 0, 0, 0); \
    acc_tr = __builtin_amdgcn_mfma_f32_16x16x32_f16(tf, rf, acc_tr, 0, 0, 0); \
    acc_rr = __builtin_amdgcn_mfma_f32_16x16x32_f16(rf, rf, acc_rr, 0, 0, 0); }

// ws layout (floats):
//   [ (b*6+slot)*528 ]       : Gram partials, slots 0..5
//   [ LOSS_OFF + b*3 + lvl ] : per-(batch,level) losses (no atomics; K3 sums)
#define LOSS_OFF (256 * 6 * 528)

// Kernel 1: 1792 blocks x 256 threads (4 waves). Block = (b, slot); wave w
// owns d-quarter w*256 (8 K-steps of 32). Verified MFMA Gram (R7/R8): lane l
// feeds row l&15, k-group l>>4; one half8 is both A and B; mfma(t,t)/(t,r)/
// (r,r). C/D: col=l&15, row=kg*4+r. Hot loop is an ISA-level load ring:
// 5 groups x 4 dwordx4 live, s_waitcnt vmcnt(16) (never 0 until tail).
__global__ __launch_bounds__(256, 2)   // 256-VGPR budget: don't collapse ring
void ntxent_partial(const float* __restrict__ ts0, const float* __restrict__ rs0,
                    const float* __restrict__ ts1, const float* __restrict__ rs1,
                    const float* __restrict__ ts2, const float* __restrict__ rs2,
                    float* __restrict__ ws)
{
    __shared__ float redTT[4][256];
    __shared__ float redTR[4][256];
    __shared__ float redRR[4][16];
    __shared__ float Gs[16][33];
    __shared__ float rn2[16], tnS[16], rnS[16];

    const int bid  = blockIdx.x;
    const int b    = bid / 7;
    const int slot = bid % 7;

    const float* tp; const float* rp; int D; int chunk0;
    if (slot < 4)      { tp = ts0; rp = rs0; D = 4096; chunk0 = slot; }
    else if (slot < 6) { tp = ts1; rp = rs1; D = 2048; chunk0 = slot - 4; }
    else               { tp = ts2; rp = rs2; D = 1024; chunk0 = 0; }

    const int t   = threadIdx.x;
    const int w   = t >> 6;
    const int l   = t & 63;
    const int row = l & 15;
    const int kg  = l >> 4;

    const size_t base = (size_t)b * 16 * D + (size_t)row * D
                      + (size_t)chunk0 * 1024 + (size_t)w * 256 + (size_t)kg * 8;
    const float* tsrc = tp + base;
    const float* rsrc = rp + base;

    f32x4 acc_tt = {0.f, 0.f, 0.f, 0.f};
    f32x4 acc_tr = {0.f, 0.f, 0.f, 0.f};
    f32x4 acc_rr = {0.f, 0.f, 0.f, 0.f};

    // ---- load ring: 8 K-steps, 4 loads each; 16-20 outstanding ----
    ISSUE(g0, 0) ISSUE(g1, 1) ISSUE(g2, 2) ISSUE(g3, 3)
    ISSUE(g4, 4) WAITVM(16); COMPUTE(g0)
    ISSUE(g5, 5) WAITVM(16); COMPUTE(g1)
    ISSUE(g6, 6) WAITVM(16); COMPUTE(g2)
    ISSUE(g7, 7) WAITVM(16); COMPUTE(g3)
    WAITVM(12);  COMPUTE(g4)
    WAITVM(8);   COMPUTE(g5)
    WAITVM(4);   COMPUTE(g6)
    WAITVM(0);   COMPUTE(g7)

    // ---- epilogue: combine 4 wave partials via LDS ----
    const int m = row;
#pragma unroll
    for (int r = 0; r < 4; ++r) {
        const int n = kg * 4 + r;
        redTT[w][n * 16 + m] = acc_tt[r];
        redTR[w][n * 16 + m] = acc_tr[r];
    }
    if ((m >> 2) == kg) redRR[w][m] = acc_rr[m & 3];
    __syncthreads();

    const int n  = t >> 4;
    const int mm = t & 15;
    const float tt = redTT[0][t] + redTT[1][t] + redTT[2][t] + redTT[3][t];
    const float tr = redTR[0][t] + redTR[1][t] + redTR[2][t] + redTR[3][t];

    if (slot != 6) {
        float* slotp = ws + (size_t)(b * 6 + slot) * 528;
        slotp[n * 32 + mm]      = tt;
        slotp[n * 32 + 16 + mm] = tr;
        if (t < 16)
            slotp[512 + t] = redRR[0][t] + redRR[1][t] + redRR[2][t] + redRR[3][t];
        return;
    }

    // ---- slot 6 (level 2): finish the loss in-kernel ----
    Gs[n][mm]      = tt;
    Gs[n][16 + mm] = tr;
    if (t < 16)
        rn2[t] = redRR[0][t] + redRR[1][t] + redRR[2][t] + redRR[3][t];
    __syncthreads();

    if (t < 16) {
        tnS[t] = fmaxf(sqrtf(Gs[t][t]), NTX_EPS);
        rnS[t] = fmaxf(sqrtf(rn2[t]), NTX_EPS);
    }
    __syncthreads();

    float loss = 0.f;
    if (t < 16) {
        const int nn = t;
        const float itn = 2.0f / tnS[nn];        // includes 1/temperature
        float lg[32];
#pragma unroll
        for (int j = 0; j < 16; ++j)
            lg[j] = Gs[nn][16 + j] * itn / rnS[j];     // s_tr row
#pragma unroll
        for (int k = 0; k < 16; ++k)
            lg[16 + k] = Gs[nn][k] * itn / tnS[k];     // s_tt row
        const float pos = lg[nn];
        float mx = -3.4e38f;
#pragma unroll
        for (int j = 0; j < 32; ++j)
            mx = (j == 16 + nn) ? mx : fmaxf(mx, lg[j]);   // exclude tt diag
        float sm = 0.f;
#pragma unroll
        for (int j = 0; j < 32; ++j)
            sm += (j == 16 + nn) ? 0.f : expf(lg[j] - mx);
        loss = logf(sm) + mx - pos;
    }
    loss += __shfl_xor(loss, 1, 64);
    loss += __shfl_xor(loss, 2, 64);
    loss += __shfl_xor(loss, 4, 64);
    loss += __shfl_xor(loss, 8, 64);
    if (t == 0) ws[LOSS_OFF + b * 3 + 2] = loss;    // no atomic
}

// Kernel 2: sum partial Grams for levels 0/1 and do the logsumexp.
__global__ __launch_bounds__(64)
void ntxent_finish(const float* __restrict__ ws_in, float* __restrict__ ws)
{
    __shared__ float G[16][33];
    __shared__ float rn2s[16];
    __shared__ float tn[16], rn[16];

    const int bid = blockIdx.x;
    const int b   = bid >> 1;
    const int lvl = bid & 1;
    const int base = b * 6 + (lvl ? 4 : 0);
    const int cnt  = lvl ? 2 : 4;
    const int l = threadIdx.x;

    for (int e = l; e < 512; e += 64) {
        float s = 0.f;
        for (int c = 0; c < cnt; ++c) s += ws_in[(size_t)(base + c) * 528 + e];
        G[e >> 5][e & 31] = s;
    }
    if (l < 16) {
        float s = 0.f;
        for (int c = 0; c < cnt; ++c) s += ws_in[(size_t)(base + c) * 528 + 512 + l];
        rn2s[l] = s;
    }
    __syncthreads();
    if (l < 16) {
        tn[l] = fmaxf(sqrtf(G[l][l]), NTX_EPS);
        rn[l] = fmaxf(sqrtf(rn2s[l]), NTX_EPS);
    }
    __syncthreads();

    float loss = 0.f;
    if (l < 16) {
        const int n = l;
        const float itn = 2.0f / tn[n];
        float lg[32];
#pragma unroll
        for (int j = 0; j < 16; ++j)
            lg[j] = G[n][16 + j] * itn / rn[j];
#pragma unroll
        for (int k = 0; k < 16; ++k)
            lg[16 + k] = G[n][k] * itn / tn[k];
        const float pos = lg[n];
        float mx = -3.4e38f;
#pragma unroll
        for (int j = 0; j < 32; ++j)
            mx = (j == 16 + n) ? mx : fmaxf(mx, lg[j]);
        float sm = 0.f;
#pragma unroll
        for (int j = 0; j < 32; ++j)
            sm += (j == 16 + n) ? 0.f : expf(lg[j] - mx);
        loss = logf(sm) + mx - pos;
    }
    loss += __shfl_xor(loss, 1, 64);
    loss += __shfl_xor(loss, 2, 64);
    loss += __shfl_xor(loss, 4, 64);
    loss += __shfl_xor(loss, 8, 64);
    if (l == 0) ws[LOSS_OFF + b * 3 + lvl] = loss;  // no atomic
}

// Kernel 3: single block sums the 768 per-(b,lvl) losses -> out[0].
__global__ __launch_bounds__(256)
void ntxent_sum(const float* __restrict__ ws, float* __restrict__ out)
{
    __shared__ float partial[4];
    const int t = threadIdx.x;
    float s = 0.f;
    for (int i = t; i < 768; i += 256) s += ws[LOSS_OFF + i];
    s += __shfl_xor(s, 1, 64);
    s += __shfl_xor(s, 2, 64);
    s += __shfl_xor(s, 4, 64);
    s += __shfl_xor(s, 8, 64);
    s += __shfl_xor(s, 16, 64);
    s += __shfl_xor(s, 32, 64);
    if ((t & 63) == 0) partial[t >> 6] = s;
    __syncthreads();
    if (t == 0)
        out[0] = (partial[0] + partial[1] + partial[2] + partial[3])
                 * (1.0f / 512.0f);
}

extern "C" void kernel_launch(void* const* d_in, const int* in_sizes, int n_in,
                              void* d_out, int out_size, void* d_ws, size_t ws_size,
                              hipStream_t stream) {
    const float* ts0 = (const float*)d_in[0];
    const float* rs0 = (const float*)d_in[1];
    const float* ts1 = (const float*)d_in[2];
    const float* rs1 = (const float*)d_in[3];
    const float* ts2 = (const float*)d_in[4];
    const float* rs2 = (const float*)d_in[5];
    float* out = (float*)d_out;
    float* ws  = (float*)d_ws;

    const int B = in_sizes[0] / (16 * 4096);   // 256
    hipLaunchKernelGGL(ntxent_partial, dim3(B * 7), dim3(256), 0, stream,
                       ts0, rs0, ts1, rs1, ts2, rs2, ws);
    hipLaunchKernelGGL(ntxent_finish, dim3(B * 2), dim3(64), 0, stream,
                       ws, ws);
    hipLaunchKernelGGL(ntxent_sum, dim3(1), dim3(256), 0, stream,
                       ws, out);
}